// Round 16
// baseline (642.620 us; speedup 1.0000x reference)
//
#include <hip/hip_runtime.h>
#include <cmath>

#define DD 64
#define TILE 64
#define TILE3 128
#define BLK 256
#define NSLOT 64

__device__ __forceinline__ float elu_f(float x) {
  return x > 0.f ? x : expm1f(x);
}
__device__ __forceinline__ float elu_fast(float x) {
  return x > 0.f ? x : __expf(x) - 1.f;
}
__device__ __forceinline__ float sigmoid_fast(float x) {
  return __builtin_amdgcn_rcpf(1.f + __expf(-x));
}

__device__ __forceinline__ void fma4(float4& a, float s, const float4 b) {
  a.x = fmaf(s, b.x, a.x);
  a.y = fmaf(s, b.y, a.y);
  a.z = fmaf(s, b.z, a.z);
  a.w = fmaf(s, b.w, a.w);
}
__device__ __forceinline__ void add4(float4& a, const float4 b) {
  a.x += b.x; a.y += b.y; a.z += b.z; a.w += b.w;
}
__device__ __forceinline__ void sqacc4(float4& a, const float4 b) {
  a.x = fmaf(b.x, b.x, a.x);
  a.y = fmaf(b.y, b.y, a.y);
  a.z = fmaf(b.z, b.z, a.z);
  a.w = fmaf(b.w, b.w, a.w);
}
__device__ __forceinline__ void scale4(float4& a, float s) {
  a.x *= s; a.y *= s; a.z *= s; a.w *= s;
}

// single-weight 64x64 micro-kernel: acc[i] (rows r0..r0+3) += xs @ wl (cols c0..c0+3)
__device__ __forceinline__ void matmul_tile(const float (*xs)[DD + 4], const float (*wl)[DD],
                                            int r0, int c0, float4 acc[4]) {
#pragma unroll 2
  for (int k0 = 0; k0 < DD; k0 += 4) {
    float4 x0 = *(const float4*)&xs[r0 + 0][k0];
    float4 x1 = *(const float4*)&xs[r0 + 1][k0];
    float4 x2 = *(const float4*)&xs[r0 + 2][k0];
    float4 x3 = *(const float4*)&xs[r0 + 3][k0];
    float4 w0 = *(const float4*)&wl[k0 + 0][c0];
    float4 w1 = *(const float4*)&wl[k0 + 1][c0];
    float4 w2 = *(const float4*)&wl[k0 + 2][c0];
    float4 w3 = *(const float4*)&wl[k0 + 3][c0];
    fma4(acc[0], x0.x, w0); fma4(acc[0], x0.y, w1); fma4(acc[0], x0.z, w2); fma4(acc[0], x0.w, w3);
    fma4(acc[1], x1.x, w0); fma4(acc[1], x1.y, w1); fma4(acc[1], x1.z, w2); fma4(acc[1], x1.w, w3);
    fma4(acc[2], x2.x, w0); fma4(acc[2], x2.y, w1); fma4(acc[2], x2.z, w2); fma4(acc[2], x2.w, w3);
    fma4(acc[3], x3.x, w0); fma4(acc[3], x3.y, w1); fma4(acc[3], x3.z, w2); fma4(acc[3], x3.w, w3);
  }
}

// 8-rows-per-thread variant: weight reads amortized over 8 rows (25% fewer LDS reads)
__device__ __forceinline__ void matmul_tile8(const float (*xs)[DD + 4], const float (*wl)[DD],
                                             int r0, int c0, float4 acc[8]) {
#pragma unroll 2
  for (int k0 = 0; k0 < DD; k0 += 4) {
    float4 w0 = *(const float4*)&wl[k0 + 0][c0];
    float4 w1 = *(const float4*)&wl[k0 + 1][c0];
    float4 w2 = *(const float4*)&wl[k0 + 2][c0];
    float4 w3 = *(const float4*)&wl[k0 + 3][c0];
#pragma unroll
    for (int i = 0; i < 8; ++i) {
      float4 xv = *(const float4*)&xs[r0 + i][k0];
      fma4(acc[i], xv.x, w0);
      fma4(acc[i], xv.y, w1);
      fma4(acc[i], xv.z, w2);
      fma4(acc[i], xv.w, w3);
    }
  }
}

// ---------------- counts (int) per molecule + atom degree ----------------
__global__ void cnt_kernel(const int* __restrict__ a2m, int na,
                           const int* __restrict__ b2m, int nb,
                           const int* __restrict__ bu, const int* __restrict__ bv,
                           int* __restrict__ cnta_i, int* __restrict__ cntb_i,
                           int* __restrict__ deg) {
  int i = blockIdx.x * blockDim.x + threadIdx.x;
  if (i < na) {
    atomicAdd(&cnta_i[a2m[i]], 1);
  } else if (i < na + nb) {
    int b = i - na;
    atomicAdd(&cntb_i[b2m[b]], 1);
    atomicAdd(&deg[bu[b]], 1);
    atomicAdd(&deg[bv[b]], 1);
  }
}

// ---------------- CSR segment allocation via wave-scan + one atomic per wave ----------------
__global__ void seg_alloc_kernel(const int* __restrict__ deg, int n,
                                 int* __restrict__ start, int* __restrict__ gcount) {
  int i = blockIdx.x * blockDim.x + threadIdx.x;
  int lane = threadIdx.x & 63;
  int d = (i < n) ? deg[i] : 0;
  int pre = d;
#pragma unroll
  for (int off = 1; off < 64; off <<= 1) {
    int t = __shfl_up(pre, off, 64);
    if (lane >= off) pre += t;
  }
  int total = __shfl(pre, 63, 64);
  int excl = pre - d;
  int base = 0;
  if (lane == 63) base = atomicAdd(gcount, total);
  base = __shfl(base, 63, 64);
  if (i < n) start[i] = base + excl;
}

// ---------------- atom adjacency fill: adj[pos] = {bond, other_atom} ----------------
__global__ void fill_kernel(const int* __restrict__ bu, const int* __restrict__ bv, int nb,
                            const int* __restrict__ start, int* __restrict__ cur,
                            int2* __restrict__ adj) {
  int b = blockIdx.x * blockDim.x + threadIdx.x;
  if (b < nb) {
    int a0 = bu[b], a1 = bv[b];
    int p = start[a0] + atomicAdd(&cur[a0], 1);
    adj[p] = make_int2(b, a1);
    int q = start[a1] + atomicAdd(&cur[a1], 1);
    adj[q] = make_int2(b, a0);
  }
}

// ---------------- mol member lists fill ----------------
__global__ void fill_mol_kernel(const int* __restrict__ a2m, int na,
                                const int* __restrict__ b2m, int nb,
                                const int* __restrict__ start_ma, int* __restrict__ cur_ma,
                                int* __restrict__ lista,
                                const int* __restrict__ start_mb, int* __restrict__ cur_mb,
                                int* __restrict__ listb) {
  int i = blockIdx.x * blockDim.x + threadIdx.x;
  if (i < na) {
    int m = a2m[i];
    lista[start_ma[m] + atomicAdd(&cur_ma[m], 1)] = i;
  } else if (i < na + nb) {
    int b = i - na;
    int m = b2m[b];
    listb[start_mb[m] + atomicAdd(&cur_mb[m], 1)] = b;
  }
}

// ---------------- dual linear: out0 = x@W0+b0, out1 = x@W1+b1 (used for u) ----------------
__global__ __launch_bounds__(BLK) void lin2_kernel(
    const float* __restrict__ x, int nrows,
    const float* __restrict__ W0, const float* __restrict__ b0, float* __restrict__ out0,
    const float* __restrict__ W1, const float* __restrict__ b1, float* __restrict__ out1) {
  __shared__ __align__(16) float xs[TILE][DD + 4];
  __shared__ __align__(16) float w0[DD][DD];
  __shared__ __align__(16) float w1[DD][DD];
  const int tid = threadIdx.x;
  const int base = blockIdx.x * TILE;
  int rows = nrows - base; if (rows > TILE) rows = TILE;
  for (int l = tid; l < DD * DD; l += BLK) {
    int r = l >> 6, c = l & 63;
    xs[r][c] = (r < rows) ? x[(size_t)(base + r) * DD + c] : 0.f;
    w0[r][c] = W0[l];
    w1[r][c] = W1[l];
  }
  __syncthreads();
  const int tr = tid >> 4, tc = tid & 15;
  const int r0 = tr * 4, c0 = tc * 4;
  float4 accA[4], accB[4];
#pragma unroll
  for (int i = 0; i < 4; ++i) {
    accA[i] = make_float4(0.f, 0.f, 0.f, 0.f);
    accB[i] = make_float4(0.f, 0.f, 0.f, 0.f);
  }
  matmul_tile(xs, w0, r0, c0, accA);
  matmul_tile(xs, w1, r0, c0, accB);
  float4 bv0 = *(const float4*)&b0[c0];
  float4 bv1 = *(const float4*)&b1[c0];
#pragma unroll
  for (int i = 0; i < 4; ++i) {
    if (r0 + i < rows) {
      size_t rb = (size_t)(base + r0 + i) * DD + c0;
      float4 o0 = accA[i]; add4(o0, bv0);
      float4 o1 = accB[i]; add4(o1, bv1);
      *(float4*)&out0[rb] = o0;
      *(float4*)&out1[rb] = o1;
    }
  }
}

// ---------------- triple linear (3-phase LDS, 8-row register blocking) ----------------
// Ah=h@W0+b0, Eh=h@W4+b4, Dh=h@W3+b3. one read of h; Dh -> out_h region.
// TILE3=128 rows, 8 rows/thread: weight LDS reads amortized 8x (vs 4x) => 25% fewer
// total LDS reads. Output written at end of each phase (one acc[8] live at a time).
// LDS = xs (34.8 KB) + 1 weight buffer (16 KB) = 50.8 KB -> 3 blocks/CU.
__global__ __launch_bounds__(BLK) void lin3_kernel(
    const float* __restrict__ x, int nrows,
    const float* __restrict__ W0, const float* __restrict__ b0, float* __restrict__ out0,
    const float* __restrict__ W1, const float* __restrict__ b1, float* __restrict__ out1,
    const float* __restrict__ W2, const float* __restrict__ b2, float* __restrict__ out2) {
  __shared__ __align__(16) float xs[TILE3][DD + 4];
  __shared__ __align__(16) float wl[DD][DD];
  const int tid = threadIdx.x;
  const int base = blockIdx.x * TILE3;
  int rows = nrows - base; if (rows > TILE3) rows = TILE3;
  for (int l = tid; l < TILE3 * DD; l += BLK) {
    int r = l >> 6, c = l & 63;
    xs[r][c] = (r < rows) ? x[(size_t)(base + r) * DD + c] : 0.f;
  }
  for (int l = tid; l < DD * DD; l += BLK) wl[l >> 6][l & 63] = W0[l];
  __syncthreads();
  const int tr = tid >> 4, tc = tid & 15;
  const int r0 = tr * 8, c0 = tc * 4;

  auto phase = [&](const float* __restrict__ bb, float* __restrict__ oo) {
    float4 acc[8];
#pragma unroll
    for (int i = 0; i < 8; ++i) acc[i] = make_float4(0.f, 0.f, 0.f, 0.f);
    matmul_tile8(xs, wl, r0, c0, acc);
    float4 bv = *(const float4*)&bb[c0];
#pragma unroll
    for (int i = 0; i < 8; ++i) {
      if (r0 + i < rows) {
        float4 o = acc[i]; add4(o, bv);
        *(float4*)&oo[(size_t)(base + r0 + i) * DD + c0] = o;
      }
    }
  };

  phase(b0, out0);
  __syncthreads();  // all reads of wl done
  for (int l = tid; l < DD * DD; l += BLK) wl[l >> 6][l & 63] = W1[l];
  __syncthreads();
  phase(b1, out1);
  __syncthreads();
  for (int l = tid; l < DD * DD; l += BLK) wl[l >> 6][l & 63] = W2[l];
  __syncthreads();
  phase(b2, out2);
}

// ---------------- bond pass 1: e_pre = (Ah[u]+Ah[v]+e@W1+b1+Cu[m])*norm ; slot BN stats ----------------
__global__ __launch_bounds__(BLK) void bond1_kernel(
    const float* __restrict__ e, int nrows, int ntiles,
    const float* __restrict__ W1, const float* __restrict__ b1,
    const float* __restrict__ Ah, const float* __restrict__ Cu,
    const int* __restrict__ bu, const int* __restrict__ bv, const int* __restrict__ b2m,
    const float* __restrict__ nrm,
    float* __restrict__ e_pre,
    float* __restrict__ psum, float* __restrict__ psq) {
  __shared__ __align__(16) float xs[TILE][DD + 4];
  __shared__ __align__(16) float wl[DD][DD];
  __shared__ int sbu[TILE], sbv[TILE], sbm[TILE];
  __shared__ float snb[TILE];
  __shared__ __align__(16) float red[16][DD];
  const int tid = threadIdx.x;
  const int tr = tid >> 4, tc = tid & 15, r0 = tr * 4, c0 = tc * 4;
  for (int l = tid; l < DD * DD; l += BLK) wl[l >> 6][l & 63] = W1[l];
  float4 bp = *(const float4*)&b1[c0];
  float4 lsum = make_float4(0.f, 0.f, 0.f, 0.f);
  float4 lsq  = make_float4(0.f, 0.f, 0.f, 0.f);
  for (int tile = blockIdx.x; tile < ntiles; tile += gridDim.x) {
    const int base = tile * TILE;
    int rows = nrows - base; if (rows > TILE) rows = TILE;
    __syncthreads();
    for (int l = tid; l < TILE * DD; l += BLK) {
      int r = l >> 6, c = l & 63;
      xs[r][c] = (r < rows) ? e[(size_t)(base + r) * DD + c] : 0.f;
    }
    if (tid < TILE) {
      bool v = tid < rows;
      int rb = base + tid;
      sbu[tid] = v ? bu[rb] : 0;
      sbv[tid] = v ? bv[rb] : 0;
      sbm[tid] = v ? b2m[rb] : 0;
      snb[tid] = v ? nrm[rb] : 0.f;
    }
    __syncthreads();
    float4 acc[4];
#pragma unroll
    for (int i = 0; i < 4; ++i) acc[i] = make_float4(0.f, 0.f, 0.f, 0.f);
    matmul_tile(xs, wl, r0, c0, acc);
#pragma unroll
    for (int i = 0; i < 4; ++i) {
      int r = r0 + i;
      if (r < rows) {
        int rb = base + r;
        float nb = snb[r];
        float4 ga = *(const float4*)&Ah[(size_t)sbu[r] * DD + c0];
        float4 gb = *(const float4*)&Ah[(size_t)sbv[r] * DD + c0];
        float4 gc = *(const float4*)&Cu[(size_t)sbm[r] * DD + c0];
        float4 o = acc[i];
        add4(o, bp); add4(o, ga); add4(o, gb); add4(o, gc);
        scale4(o, nb);
        add4(lsum, o); sqacc4(lsq, o);
        *(float4*)&e_pre[(size_t)rb * DD + c0] = o;
      }
    }
  }
  __syncthreads();
  *(float4*)&red[tr][c0] = lsum;
  __syncthreads();
  const int slot = (blockIdx.x & (NSLOT - 1)) * DD;
  if (tid < DD) {
    float s = 0.f;
#pragma unroll
    for (int t = 0; t < 16; ++t) s += red[t][tid];
    atomicAdd(&psum[slot + tid], s);
  }
  __syncthreads();
  *(float4*)&red[tr][c0] = lsq;
  __syncthreads();
  if (tid < DD) {
    float s = 0.f;
#pragma unroll
    for (int t = 0; t < 16; ++t) s += red[t][tid];
    atomicAdd(&psq[slot + tid], s);
  }
}

// ---------------- BN finalize: scale/shift (direct stats) ----------------
__global__ void bnfinal_kernel(const float* __restrict__ ssum, const float* __restrict__ ssq,
                               const float* __restrict__ gamma, const float* __restrict__ beta,
                               float invN, float* __restrict__ scale, float* __restrict__ shift) {
  int j = threadIdx.x;
  float m = ssum[j] * invN;
  float v = ssq[j] * invN - m * m;
  float sc = gamma[j] * rsqrtf(v + 1e-5f);
  scale[j] = sc;
  shift[j] = beta[j] - m * sc;
}

// ---------------- BN finalize from NSLOT slot partials ----------------
__global__ void bnfinal_slots_kernel(const float* __restrict__ psum, const float* __restrict__ psq,
                                     const float* __restrict__ gamma, const float* __restrict__ beta,
                                     float invN, float* __restrict__ scale, float* __restrict__ shift) {
  int j = threadIdx.x;
  float s = 0.f, q = 0.f;
#pragma unroll 8
  for (int t = 0; t < NSLOT; ++t) {
    s += psum[t * DD + j];
    q += psq[t * DD + j];
  }
  float m = s * invN;
  float v = q * invN - m * m;
  float sc = gamma[j] * rsqrtf(v + 1e-5f);
  scale[j] = sc;
  shift[j] = beta[j] - m * sc;
}

// ---------------- vectorized BN+ELU in place (used for u only) ----------------
__global__ void bn_elu_vec_kernel(float* __restrict__ x, long n4,
                                  const float* __restrict__ scale,
                                  const float* __restrict__ shift) {
  long stride = (long)gridDim.x * blockDim.x;
  for (long i = blockIdx.x * (long)blockDim.x + threadIdx.x; i < n4; i += stride) {
    float4 v = ((float4*)x)[i];
    int c0 = (int)((i & 15) << 2);
    float4 sc = *(const float4*)&scale[c0];
    float4 sh = *(const float4*)&shift[c0];
    v.x = elu_f(fmaf(v.x, sc.x, sh.x));
    v.y = elu_f(fmaf(v.y, sc.y, sh.y));
    v.z = elu_f(fmaf(v.z, sc.z, sh.z));
    v.w = elu_f(fmaf(v.w, sc.w, sh.w));
    ((float4*)x)[i] = v;
  }
}

// ---------------- fused pull aggregation + atom update ----------------
// ONE WAVE PER ATOM, exact grid, lane = column. Pairwise-unrolled edge loop.
// Gathers RAW e_pre, applies BN+ELU inline (fast-exp variant):
//  gate = sig(elu(e_pre*sc_e+sh_e))
//  h_pre = (Dhb[a] + sum(gate*Eh[other])/(sum(gate)+eps) + Fu[a2m]) * norm_atom
// Dhb aliases hpre (out_h): each thread reads its element then overwrites it.
__global__ __launch_bounds__(BLK) void agg_fused_kernel(
    const float* __restrict__ e_pre, const float* __restrict__ Eh,
    const float* __restrict__ Dhb, const float* __restrict__ Fu,
    const int* __restrict__ a2m, const float* __restrict__ nrm,
    const float* __restrict__ sc_e, const float* __restrict__ sh_e,
    const int* __restrict__ start, const int* __restrict__ deg,
    const int2* __restrict__ adj, int na,
    float* __restrict__ hpre,
    float* __restrict__ psum, float* __restrict__ psq) {
  const int tid = threadIdx.x;
  const int lane = tid & 63;
  const int wv = tid >> 6;
  const int wid = blockIdx.x * (BLK >> 6) + wv;
  float lsum = 0.f, lsq = 0.f;
  if (wid < na) {
    // independent row-level loads — issue ahead of the edge chain
    float dh = Dhb[(size_t)wid * DD + lane];
    float fu = Fu[(size_t)a2m[wid] * DD + lane];
    float nr = nrm[wid];
    float sce = sc_e[lane], she = sh_e[lane];
    int s = start[wid], d = deg[wid];
    float num = 0.f, den = 0.f;
    int k = 0;
    for (; k + 2 <= d; k += 2) {
      int2 e0 = adj[s + k];
      int2 e1 = adj[s + k + 1];
      float ep0 = e_pre[(size_t)e0.x * DD + lane];
      float eh0 = Eh[(size_t)e0.y * DD + lane];
      float ep1 = e_pre[(size_t)e1.x * DD + lane];
      float eh1 = Eh[(size_t)e1.y * DD + lane];
      float sg0 = sigmoid_fast(elu_fast(fmaf(ep0, sce, she)));
      float sg1 = sigmoid_fast(elu_fast(fmaf(ep1, sce, she)));
      num = fmaf(sg0, eh0, num); den += sg0;
      num = fmaf(sg1, eh1, num); den += sg1;
    }
    if (k < d) {
      int2 e0 = adj[s + k];
      float ep = e_pre[(size_t)e0.x * DD + lane];
      float eh = Eh[(size_t)e0.y * DD + lane];
      float sg = sigmoid_fast(elu_fast(fmaf(ep, sce, she)));
      num = fmaf(sg, eh, num); den += sg;
    }
    float o = (dh + num / (den + 1e-6f) + fu) * nr;
    hpre[(size_t)wid * DD + lane] = o;
    lsum = o;
    lsq = o * o;
  }
  __shared__ __align__(16) float red[BLK / 64][DD];
  red[wv][lane] = lsum;
  __syncthreads();
  if (tid < DD) {
    float s4 = red[0][tid] + red[1][tid] + red[2][tid] + red[3][tid];
    atomicAdd(&psum[(blockIdx.x & (NSLOT - 1)) * DD + tid], s4);
  }
  __syncthreads();
  red[wv][lane] = lsq;
  __syncthreads();
  if (tid < DD) {
    float s4 = red[0][tid] + red[1][tid] + red[2][tid] + red[3][tid];
    atomicAdd(&psq[(blockIdx.x & (NSLOT - 1)) * DD + tid], s4);
  }
}

// ---------------- merged mol row-sums + BN+ELU applier (4-way MLP unroll) ----------------
__global__ __launch_bounds__(BLK) void molsum2_kernel(
    float* __restrict__ rowsA, const int* __restrict__ start_ma,
    const int* __restrict__ cnta, const int* __restrict__ lista,
    const float* __restrict__ scA, const float* __restrict__ shA,
    float* __restrict__ rowsB, const int* __restrict__ start_mb,
    const int* __restrict__ cntb, const int* __restrict__ listb,
    const float* __restrict__ scB, const float* __restrict__ shB,
    int nm, float* __restrict__ msa, float* __restrict__ msb) {
  int wid = (int)((blockIdx.x * (unsigned)blockDim.x + threadIdx.x) >> 6);
  int lane = threadIdx.x & 63;
  if (wid >= 2 * nm) return;
  float* rows;
  const int* list;
  float* out;
  float sc, sh;
  int m, s, c;
  if (wid < nm) {
    m = wid; rows = rowsA; list = lista; out = msa;
    s = start_ma[m]; c = cnta[m];
    sc = scA[lane]; sh = shA[lane];
  } else {
    m = wid - nm; rows = rowsB; list = listb; out = msb;
    s = start_mb[m]; c = cntb[m];
    sc = scB[lane]; sh = shB[lane];
  }
  float acc = 0.f;
  int k = 0;
  for (; k + 4 <= c; k += 4) {
    int j0 = list[s + k], j1 = list[s + k + 1], j2 = list[s + k + 2], j3 = list[s + k + 3];
    size_t i0 = (size_t)j0 * DD + lane;
    size_t i1 = (size_t)j1 * DD + lane;
    size_t i2 = (size_t)j2 * DD + lane;
    size_t i3 = (size_t)j3 * DD + lane;
    float v0 = rows[i0];
    float v1 = rows[i1];
    float v2 = rows[i2];
    float v3 = rows[i3];
    float t0 = elu_fast(fmaf(v0, sc, sh));
    float t1 = elu_fast(fmaf(v1, sc, sh));
    float t2 = elu_fast(fmaf(v2, sc, sh));
    float t3 = elu_fast(fmaf(v3, sc, sh));
    rows[i0] = t0;
    rows[i1] = t1;
    rows[i2] = t2;
    rows[i3] = t3;
    acc += (t0 + t1) + (t2 + t3);
  }
  for (; k + 2 <= c; k += 2) {
    size_t i0 = (size_t)list[s + k] * DD + lane;
    size_t i1 = (size_t)list[s + k + 1] * DD + lane;
    float v0 = rows[i0];
    float v1 = rows[i1];
    float t0 = elu_fast(fmaf(v0, sc, sh));
    float t1 = elu_fast(fmaf(v1, sc, sh));
    rows[i0] = t0;
    rows[i1] = t1;
    acc += t0 + t1;
  }
  if (k < c) {
    size_t i0 = (size_t)list[s + k] * DD + lane;
    float t0 = elu_fast(fmaf(rows[i0], sc, sh));
    rows[i0] = t0;
    acc += t0;
  }
  out[(size_t)m * DD + lane] = acc;
}

// ---------------- global pass: u_pre = msa/cnt_a@W6 [+b6] + msb/cnt_b@W7 [+b7] + u@W8+b8 ----------------
__global__ __launch_bounds__(BLK) void global1_kernel(
    const float* __restrict__ u, int nrows,
    const float* __restrict__ W6, const float* __restrict__ W7, const float* __restrict__ W8,
    const float* __restrict__ b6, const float* __restrict__ b7, const float* __restrict__ b8,
    const float* __restrict__ msa, const float* __restrict__ msb,
    const int* __restrict__ cnta, const int* __restrict__ cntb,
    float* __restrict__ upre,
    float* __restrict__ ssum, float* __restrict__ ssq) {
  __shared__ __align__(16) float xsu[TILE][DD + 4];
  __shared__ __align__(16) float xsa[TILE][DD + 4];
  __shared__ __align__(16) float xsb[TILE][DD + 4];
  __shared__ __align__(16) float w6s[DD][DD];
  __shared__ __align__(16) float w7s[DD][DD];
  __shared__ __align__(16) float w8s[DD][DD];
  __shared__ float sfa[TILE], sfb[TILE];   // bias masks (cnt>0)
  __shared__ __align__(16) float red[16][DD];
  const int tid = threadIdx.x;
  const int base = blockIdx.x * TILE;
  int rows = nrows - base; if (rows > TILE) rows = TILE;
  for (int l = tid; l < DD * DD; l += BLK) {
    int r = l >> 6, c = l & 63;
    w6s[r][c] = W6[l];
    w7s[r][c] = W7[l];
    w8s[r][c] = W8[l];
  }
  for (int l = tid; l < TILE * DD; l += BLK) {
    int r = l >> 6, c = l & 63;
    bool v = r < rows;
    float ca = 1.f, cb = 1.f;
    if (v) {
      int ia = cnta[base + r], ib = cntb[base + r];
      ca = ia > 0 ? (float)ia : 1.f;
      cb = ib > 0 ? (float)ib : 1.f;
    }
    xsu[r][c] = v ? u[(size_t)(base + r) * DD + c] : 0.f;
    xsa[r][c] = v ? msa[(size_t)(base + r) * DD + c] / ca : 0.f;
    xsb[r][c] = v ? msb[(size_t)(base + r) * DD + c] / cb : 0.f;
  }
  if (tid < TILE) {
    bool v = tid < rows;
    sfa[tid] = (v && cnta[base + tid] > 0) ? 1.f : 0.f;
    sfb[tid] = (v && cntb[base + tid] > 0) ? 1.f : 0.f;
  }
  __syncthreads();
  const int tr = tid >> 4, tc = tid & 15, r0 = tr * 4, c0 = tc * 4;
  float4 acc[4];
#pragma unroll
  for (int i = 0; i < 4; ++i) acc[i] = make_float4(0.f, 0.f, 0.f, 0.f);
  matmul_tile(xsu, w8s, r0, c0, acc);
  matmul_tile(xsa, w6s, r0, c0, acc);
  matmul_tile(xsb, w7s, r0, c0, acc);
  float4 b6v = *(const float4*)&b6[c0];
  float4 b7v = *(const float4*)&b7[c0];
  float4 b8v = *(const float4*)&b8[c0];
  float4 lsum = make_float4(0.f, 0.f, 0.f, 0.f);
  float4 lsq  = make_float4(0.f, 0.f, 0.f, 0.f);
#pragma unroll
  for (int i = 0; i < 4; ++i) {
    int r = r0 + i;
    if (r < rows) {
      size_t rb = (size_t)(base + r) * DD + c0;
      float fa = sfa[r], fb = sfb[r];
      float4 o = acc[i];
      o.x += b8v.x + fa * b6v.x + fb * b7v.x;
      o.y += b8v.y + fa * b6v.y + fb * b7v.y;
      o.z += b8v.z + fa * b6v.z + fb * b7v.z;
      o.w += b8v.w + fa * b6v.w + fb * b7v.w;
      add4(lsum, o); sqacc4(lsq, o);
      *(float4*)&upre[rb] = o;
    }
  }
  __syncthreads();
  *(float4*)&red[tr][c0] = lsum;
  __syncthreads();
  if (tid < DD) {
    float s = 0.f;
#pragma unroll
    for (int t = 0; t < 16; ++t) s += red[t][tid];
    atomicAdd(&ssum[tid], s);
  }
  __syncthreads();
  *(float4*)&red[tr][c0] = lsq;
  __syncthreads();
  if (tid < DD) {
    float s = 0.f;
#pragma unroll
    for (int t = 0; t < 16; ++t) s += red[t][tid];
    atomicAdd(&ssq[tid], s);
  }
}

extern "C" void kernel_launch(void* const* d_in, const int* in_sizes, int n_in,
                              void* d_out, int out_size, void* d_ws, size_t ws_size,
                              hipStream_t stream) {
  const float* h         = (const float*)d_in[0];
  const float* e         = (const float*)d_in[1];
  const float* u         = (const float*)d_in[2];
  const float* norm_atom = (const float*)d_in[3];
  const float* norm_bond = (const float*)d_in[4];
  const float* Ws        = (const float*)d_in[5];
  const float* bsarr     = (const float*)d_in[6];
  const float* bn_gamma  = (const float*)d_in[7];
  const float* bn_beta   = (const float*)d_in[8];
  const int* bond_u      = (const int*)d_in[9];
  const int* bond_v      = (const int*)d_in[10];
  const int* a2m         = (const int*)d_in[11];
  const int* b2m         = (const int*)d_in[12];

  const int NA = in_sizes[0] / DD;
  const int NB = in_sizes[1] / DD;
  const int NM = in_sizes[2] / DD;

  float* out_h = (float*)d_out;
  float* out_e = out_h + (size_t)NA * DD;
  float* out_u = out_e + (size_t)NB * DD;

  // ---- workspace layout (~146 MB) ----
  float* f     = (float*)d_ws;
  float* Ah    = f;                            // NA*64
  float* Eh    = Ah + (size_t)NA * DD;         // NA*64
  float* Cu    = Eh + (size_t)NA * DD;         // NM*64
  float* Fu    = Cu + (size_t)NM * DD;         // NM*64
  float* msa   = Fu + (size_t)NM * DD;         // NM*64 (mol sum of h_new)
  float* msb   = msa + (size_t)NM * DD;        // NM*64 (mol sum of e_new)
  // Dh lives in out_h's region (dead until agg reads-then-overwrites it)
  float* Dhb   = out_h;
  // zeroed block starts here:
  float* stats = msb + (size_t)NM * DD;        // 256: sum_u, sq_u, pad
  float* sum_u = stats, *sq_u = stats + 64;
  float* psum_h = stats + 256;                 // NSLOT*64
  float* psq_h  = psum_h + NSLOT * DD;         // NSLOT*64
  float* psum_e = psq_h + NSLOT * DD;          // NSLOT*64
  float* psq_e  = psum_e + NSLOT * DD;         // NSLOT*64
  int* deg     = (int*)(psq_e + NSLOT * DD);   // NA
  int* cur     = deg + NA;                     // NA
  int* cnta_i  = cur + NA;                     // NM
  int* cntb_i  = cnta_i + NM;                  // NM
  int* cur_ma  = cntb_i + NM;                  // NM
  int* cur_mb  = cur_ma + NM;                  // NM
  int* gcounts = cur_mb + NM;                  // 4
  // zeroed block ends here.
  float* bnp   = (float*)(gcounts + 4);        // 6*64
  float* sc_e = bnp, *sh_e = bnp + 64;
  float* sc_h = bnp + 128, *sh_h = bnp + 192;
  float* sc_u = bnp + 256, *sh_u = bnp + 320;
  int* start    = (int*)(bnp + 384);           // NA
  int* start_ma = start + NA;                  // NM
  int* start_mb = start_ma + NM;               // NM
  int* lista    = start_mb + NM;               // NA
  int* listb    = lista + NA;                  // NB
  int2* adj     = (int2*)(listb + NB);         // 2*NB (8B each)

  const float* W0 = Ws + 0 * 4096; const float* b0 = bsarr + 0 * 64;
  const float* W1 = Ws + 1 * 4096; const float* b1 = bsarr + 1 * 64;
  const float* W2 = Ws + 2 * 4096; const float* b2 = bsarr + 2 * 64;
  const float* W3 = Ws + 3 * 4096; const float* b3 = bsarr + 3 * 64;
  const float* W4 = Ws + 4 * 4096; const float* b4 = bsarr + 4 * 64;
  const float* W5 = Ws + 5 * 4096; const float* b5 = bsarr + 5 * 64;
  const float* W6 = Ws + 6 * 4096; const float* b6 = bsarr + 6 * 64;
  const float* W7 = Ws + 7 * 4096; const float* b7 = bsarr + 7 * 64;
  const float* W8 = Ws + 8 * 4096; const float* b8 = bsarr + 8 * 64;

  const int tiles3_a = (NA + TILE3 - 1) / TILE3;
  const int tiles_b = (NB + TILE - 1) / TILE;
  const int tiles_m = (NM + TILE - 1) / TILE;

  // zero: stats(256) + 4 slot-partial arrays + deg + cur + mol counters + gcounts (contiguous)
  size_t zbytes = (256 + (size_t)NSLOT * DD * 4) * sizeof(float)
                + ((size_t)NA * 2 + (size_t)NM * 4 + 4) * sizeof(int);
  hipMemsetAsync(stats, 0, zbytes, stream);

  // counts + degrees
  cnt_kernel<<<(NA + NB + BLK - 1) / BLK, BLK, 0, stream>>>(a2m, NA, b2m, NB,
                                                            bond_u, bond_v,
                                                            cnta_i, cntb_i, deg);
  // CSR builds
  seg_alloc_kernel<<<(NA + BLK - 1) / BLK, BLK, 0, stream>>>(deg, NA, start, gcounts + 0);
  seg_alloc_kernel<<<(NM + BLK - 1) / BLK, BLK, 0, stream>>>(cnta_i, NM, start_ma, gcounts + 1);
  seg_alloc_kernel<<<(NM + BLK - 1) / BLK, BLK, 0, stream>>>(cntb_i, NM, start_mb, gcounts + 2);
  fill_kernel<<<(NB + BLK - 1) / BLK, BLK, 0, stream>>>(bond_u, bond_v, NB, start, cur, adj);
  fill_mol_kernel<<<(NA + NB + BLK - 1) / BLK, BLK, 0, stream>>>(a2m, NA, b2m, NB,
                                                                 start_ma, cur_ma, lista,
                                                                 start_mb, cur_mb, listb);

  // triple linear on h (3-phase LDS, 8-row blocking): Ah, Eh (ws) + Dh (out_h region)
  lin3_kernel<<<tiles3_a, BLK, 0, stream>>>(h, NA, W0, b0, Ah, W4, b4, Eh, W3, b3, Dhb);
  lin2_kernel<<<tiles_m, BLK, 0, stream>>>(u, NM, W2, b2, Cu, W5, b5, Fu);

  int nblk_b = tiles_b < 2048 ? tiles_b : 2048;
  bond1_kernel<<<nblk_b, BLK, 0, stream>>>(e, NB, tiles_b, W1, b1, Ah, Cu,
                                           bond_u, bond_v, b2m, norm_bond,
                                           out_e, psum_e, psq_e);
  bnfinal_slots_kernel<<<1, 64, 0, stream>>>(psum_e, psq_e, bn_gamma + 0, bn_beta + 0,
                                             1.f / (float)NB, sc_e, sh_e);

  // fused pull aggregation + atom update -> out_h = h_pre ; slot-partial BN stats.
  agg_fused_kernel<<<(NA + 3) / 4, BLK, 0, stream>>>(out_e, Eh, Dhb, Fu, a2m, norm_atom,
                                                     sc_e, sh_e,
                                                     start, deg, adj, NA,
                                                     out_h, psum_h, psq_h);
  bnfinal_slots_kernel<<<1, 64, 0, stream>>>(psum_h, psq_h, bn_gamma + 64, bn_beta + 64,
                                             1.f / (float)NA, sc_h, sh_h);

  // merged mol row-sums + BN+ELU applier: transforms out_h (h_pre->h_new) and
  // out_e (e_pre->e_new) in place while accumulating msa/msb. No atomics.
  molsum2_kernel<<<(2 * NM + 3) / 4, BLK, 0, stream>>>(out_h, start_ma, cnta_i, lista, sc_h, sh_h,
                                                       out_e, start_mb, cntb_i, listb, sc_e, sh_e,
                                                       NM, msa, msb);

  global1_kernel<<<tiles_m, BLK, 0, stream>>>(u, NM, W6, W7, W8, b6, b7, b8,
                                              msa, msb, cnta_i, cntb_i,
                                              out_u, sum_u, sq_u);
  bnfinal_kernel<<<1, 64, 0, stream>>>(sum_u, sq_u, bn_gamma + 128, bn_beta + 128,
                                       1.f / (float)NM, sc_u, sh_u);
  {
    long n4 = (long)NM * (DD / 4);
    int blocks = (int)((n4 + BLK - 1) / BLK); if (blocks > 2048) blocks = 2048;
    bn_elu_vec_kernel<<<blocks, BLK, 0, stream>>>(out_u, n4, sc_u, sh_u);
  }
}

// Round 17
// 597.756 us; speedup vs baseline: 1.0751x; 1.0751x over previous
//
#include <hip/hip_runtime.h>
#include <cmath>

#define DD 64
#define TILE 64
#define BLK 256
#define NSLOT 64

__device__ __forceinline__ float elu_f(float x) {
  return x > 0.f ? x : expm1f(x);
}
__device__ __forceinline__ float elu_fast(float x) {
  return x > 0.f ? x : __expf(x) - 1.f;
}
__device__ __forceinline__ float sigmoid_fast(float x) {
  return __builtin_amdgcn_rcpf(1.f + __expf(-x));
}

__device__ __forceinline__ void fma4(float4& a, float s, const float4 b) {
  a.x = fmaf(s, b.x, a.x);
  a.y = fmaf(s, b.y, a.y);
  a.z = fmaf(s, b.z, a.z);
  a.w = fmaf(s, b.w, a.w);
}
__device__ __forceinline__ void add4(float4& a, const float4 b) {
  a.x += b.x; a.y += b.y; a.z += b.z; a.w += b.w;
}
__device__ __forceinline__ void sqacc4(float4& a, const float4 b) {
  a.x = fmaf(b.x, b.x, a.x);
  a.y = fmaf(b.y, b.y, a.y);
  a.z = fmaf(b.z, b.z, a.z);
  a.w = fmaf(b.w, b.w, a.w);
}
__device__ __forceinline__ void scale4(float4& a, float s) {
  a.x *= s; a.y *= s; a.z *= s; a.w *= s;
}

// single-weight 64x64 micro-kernel: acc[i] (rows r0..r0+3) += xs @ wl (cols c0..c0+3)
__device__ __forceinline__ void matmul_tile(const float (*xs)[DD + 4], const float (*wl)[DD],
                                            int r0, int c0, float4 acc[4]) {
#pragma unroll 2
  for (int k0 = 0; k0 < DD; k0 += 4) {
    float4 x0 = *(const float4*)&xs[r0 + 0][k0];
    float4 x1 = *(const float4*)&xs[r0 + 1][k0];
    float4 x2 = *(const float4*)&xs[r0 + 2][k0];
    float4 x3 = *(const float4*)&xs[r0 + 3][k0];
    float4 w0 = *(const float4*)&wl[k0 + 0][c0];
    float4 w1 = *(const float4*)&wl[k0 + 1][c0];
    float4 w2 = *(const float4*)&wl[k0 + 2][c0];
    float4 w3 = *(const float4*)&wl[k0 + 3][c0];
    fma4(acc[0], x0.x, w0); fma4(acc[0], x0.y, w1); fma4(acc[0], x0.z, w2); fma4(acc[0], x0.w, w3);
    fma4(acc[1], x1.x, w0); fma4(acc[1], x1.y, w1); fma4(acc[1], x1.z, w2); fma4(acc[1], x1.w, w3);
    fma4(acc[2], x2.x, w0); fma4(acc[2], x2.y, w1); fma4(acc[2], x2.z, w2); fma4(acc[2], x2.w, w3);
    fma4(acc[3], x3.x, w0); fma4(acc[3], x3.y, w1); fma4(acc[3], x3.z, w2); fma4(acc[3], x3.w, w3);
  }
}

// ---------------- counts (int) per molecule + atom degree ----------------
__global__ void cnt_kernel(const int* __restrict__ a2m, int na,
                           const int* __restrict__ b2m, int nb,
                           const int* __restrict__ bu, const int* __restrict__ bv,
                           int* __restrict__ cnta_i, int* __restrict__ cntb_i,
                           int* __restrict__ deg) {
  int i = blockIdx.x * blockDim.x + threadIdx.x;
  if (i < na) {
    atomicAdd(&cnta_i[a2m[i]], 1);
  } else if (i < na + nb) {
    int b = i - na;
    atomicAdd(&cntb_i[b2m[b]], 1);
    atomicAdd(&deg[bu[b]], 1);
    atomicAdd(&deg[bv[b]], 1);
  }
}

// ---------------- CSR segment allocation via wave-scan + one atomic per wave ----------------
__global__ void seg_alloc_kernel(const int* __restrict__ deg, int n,
                                 int* __restrict__ start, int* __restrict__ gcount) {
  int i = blockIdx.x * blockDim.x + threadIdx.x;
  int lane = threadIdx.x & 63;
  int d = (i < n) ? deg[i] : 0;
  int pre = d;
#pragma unroll
  for (int off = 1; off < 64; off <<= 1) {
    int t = __shfl_up(pre, off, 64);
    if (lane >= off) pre += t;
  }
  int total = __shfl(pre, 63, 64);
  int excl = pre - d;
  int base = 0;
  if (lane == 63) base = atomicAdd(gcount, total);
  base = __shfl(base, 63, 64);
  if (i < n) start[i] = base + excl;
}

// ---------------- atom adjacency fill: adj[pos] = {bond, other_atom} ----------------
__global__ void fill_kernel(const int* __restrict__ bu, const int* __restrict__ bv, int nb,
                            const int* __restrict__ start, int* __restrict__ cur,
                            int2* __restrict__ adj) {
  int b = blockIdx.x * blockDim.x + threadIdx.x;
  if (b < nb) {
    int a0 = bu[b], a1 = bv[b];
    int p = start[a0] + atomicAdd(&cur[a0], 1);
    adj[p] = make_int2(b, a1);
    int q = start[a1] + atomicAdd(&cur[a1], 1);
    adj[q] = make_int2(b, a0);
  }
}

// ---------------- mol member lists fill ----------------
__global__ void fill_mol_kernel(const int* __restrict__ a2m, int na,
                                const int* __restrict__ b2m, int nb,
                                const int* __restrict__ start_ma, int* __restrict__ cur_ma,
                                int* __restrict__ lista,
                                const int* __restrict__ start_mb, int* __restrict__ cur_mb,
                                int* __restrict__ listb) {
  int i = blockIdx.x * blockDim.x + threadIdx.x;
  if (i < na) {
    int m = a2m[i];
    lista[start_ma[m] + atomicAdd(&cur_ma[m], 1)] = i;
  } else if (i < na + nb) {
    int b = i - na;
    int m = b2m[b];
    listb[start_mb[m] + atomicAdd(&cur_mb[m], 1)] = b;
  }
}

// ---------------- dual linear: out0 = x@W0+b0, out1 = x@W1+b1 (used for u) ----------------
__global__ __launch_bounds__(BLK) void lin2_kernel(
    const float* __restrict__ x, int nrows,
    const float* __restrict__ W0, const float* __restrict__ b0, float* __restrict__ out0,
    const float* __restrict__ W1, const float* __restrict__ b1, float* __restrict__ out1) {
  __shared__ __align__(16) float xs[TILE][DD + 4];
  __shared__ __align__(16) float w0[DD][DD];
  __shared__ __align__(16) float w1[DD][DD];
  const int tid = threadIdx.x;
  const int base = blockIdx.x * TILE;
  int rows = nrows - base; if (rows > TILE) rows = TILE;
  for (int l = tid; l < DD * DD; l += BLK) {
    int r = l >> 6, c = l & 63;
    xs[r][c] = (r < rows) ? x[(size_t)(base + r) * DD + c] : 0.f;
    w0[r][c] = W0[l];
    w1[r][c] = W1[l];
  }
  __syncthreads();
  const int tr = tid >> 4, tc = tid & 15;
  const int r0 = tr * 4, c0 = tc * 4;
  float4 accA[4], accB[4];
#pragma unroll
  for (int i = 0; i < 4; ++i) {
    accA[i] = make_float4(0.f, 0.f, 0.f, 0.f);
    accB[i] = make_float4(0.f, 0.f, 0.f, 0.f);
  }
  matmul_tile(xs, w0, r0, c0, accA);
  matmul_tile(xs, w1, r0, c0, accB);
  float4 bv0 = *(const float4*)&b0[c0];
  float4 bv1 = *(const float4*)&b1[c0];
#pragma unroll
  for (int i = 0; i < 4; ++i) {
    if (r0 + i < rows) {
      size_t rb = (size_t)(base + r0 + i) * DD + c0;
      float4 o0 = accA[i]; add4(o0, bv0);
      float4 o1 = accB[i]; add4(o1, bv1);
      *(float4*)&out0[rb] = o0;
      *(float4*)&out1[rb] = o1;
    }
  }
}

// ---------------- triple linear (3-phase LDS, single weight buffer) ----------------
// Ah=h@W0+b0, Eh=h@W4+b4, Dh=h@W3+b3. one read of h; Dh -> out_h region.
// LDS = xs (17.4 KB) + 1 weight buffer (16 KB) = 33.8 KB -> 4 blocks/CU.
__global__ __launch_bounds__(BLK) void lin3_kernel(
    const float* __restrict__ x, int nrows,
    const float* __restrict__ W0, const float* __restrict__ b0, float* __restrict__ out0,
    const float* __restrict__ W1, const float* __restrict__ b1, float* __restrict__ out1,
    const float* __restrict__ W2, const float* __restrict__ b2, float* __restrict__ out2) {
  __shared__ __align__(16) float xs[TILE][DD + 4];
  __shared__ __align__(16) float wl[DD][DD];
  const int tid = threadIdx.x;
  const int base = blockIdx.x * TILE;
  int rows = nrows - base; if (rows > TILE) rows = TILE;
  for (int l = tid; l < DD * DD; l += BLK) {
    int r = l >> 6, c = l & 63;
    xs[r][c] = (r < rows) ? x[(size_t)(base + r) * DD + c] : 0.f;
    wl[r][c] = W0[l];
  }
  __syncthreads();
  const int tr = tid >> 4, tc = tid & 15;
  const int r0 = tr * 4, c0 = tc * 4;
  float4 accA[4], accB[4], accC[4];
#pragma unroll
  for (int i = 0; i < 4; ++i) {
    accA[i] = make_float4(0.f, 0.f, 0.f, 0.f);
    accB[i] = make_float4(0.f, 0.f, 0.f, 0.f);
    accC[i] = make_float4(0.f, 0.f, 0.f, 0.f);
  }
  matmul_tile(xs, wl, r0, c0, accA);
  __syncthreads();
  for (int l = tid; l < DD * DD; l += BLK) wl[l >> 6][l & 63] = W1[l];
  __syncthreads();
  matmul_tile(xs, wl, r0, c0, accB);
  __syncthreads();
  for (int l = tid; l < DD * DD; l += BLK) wl[l >> 6][l & 63] = W2[l];
  __syncthreads();
  matmul_tile(xs, wl, r0, c0, accC);
  float4 bv0 = *(const float4*)&b0[c0];
  float4 bv1 = *(const float4*)&b1[c0];
  float4 bv2 = *(const float4*)&b2[c0];
#pragma unroll
  for (int i = 0; i < 4; ++i) {
    if (r0 + i < rows) {
      size_t rb = (size_t)(base + r0 + i) * DD + c0;
      float4 o0 = accA[i]; add4(o0, bv0);
      float4 o1 = accB[i]; add4(o1, bv1);
      float4 o2 = accC[i]; add4(o2, bv2);
      *(float4*)&out0[rb] = o0;
      *(float4*)&out1[rb] = o1;
      *(float4*)&out2[rb] = o2;
    }
  }
}

// ---------------- bond pass 1: e_pre = (Ah[u]+Ah[v]+e@W1+b1+Cu[m])*norm ; slot BN stats ----------------
__global__ __launch_bounds__(BLK) void bond1_kernel(
    const float* __restrict__ e, int nrows, int ntiles,
    const float* __restrict__ W1, const float* __restrict__ b1,
    const float* __restrict__ Ah, const float* __restrict__ Cu,
    const int* __restrict__ bu, const int* __restrict__ bv, const int* __restrict__ b2m,
    const float* __restrict__ nrm,
    float* __restrict__ e_pre,
    float* __restrict__ psum, float* __restrict__ psq) {
  __shared__ __align__(16) float xs[TILE][DD + 4];
  __shared__ __align__(16) float wl[DD][DD];
  __shared__ int sbu[TILE], sbv[TILE], sbm[TILE];
  __shared__ float snb[TILE];
  __shared__ __align__(16) float red[16][DD];
  const int tid = threadIdx.x;
  const int tr = tid >> 4, tc = tid & 15, r0 = tr * 4, c0 = tc * 4;
  for (int l = tid; l < DD * DD; l += BLK) wl[l >> 6][l & 63] = W1[l];
  float4 bp = *(const float4*)&b1[c0];
  float4 lsum = make_float4(0.f, 0.f, 0.f, 0.f);
  float4 lsq  = make_float4(0.f, 0.f, 0.f, 0.f);
  for (int tile = blockIdx.x; tile < ntiles; tile += gridDim.x) {
    const int base = tile * TILE;
    int rows = nrows - base; if (rows > TILE) rows = TILE;
    __syncthreads();
    for (int l = tid; l < TILE * DD; l += BLK) {
      int r = l >> 6, c = l & 63;
      xs[r][c] = (r < rows) ? e[(size_t)(base + r) * DD + c] : 0.f;
    }
    if (tid < TILE) {
      bool v = tid < rows;
      int rb = base + tid;
      sbu[tid] = v ? bu[rb] : 0;
      sbv[tid] = v ? bv[rb] : 0;
      sbm[tid] = v ? b2m[rb] : 0;
      snb[tid] = v ? nrm[rb] : 0.f;
    }
    __syncthreads();
    float4 acc[4];
#pragma unroll
    for (int i = 0; i < 4; ++i) acc[i] = make_float4(0.f, 0.f, 0.f, 0.f);
    matmul_tile(xs, wl, r0, c0, acc);
#pragma unroll
    for (int i = 0; i < 4; ++i) {
      int r = r0 + i;
      if (r < rows) {
        int rb = base + r;
        float nb = snb[r];
        float4 ga = *(const float4*)&Ah[(size_t)sbu[r] * DD + c0];
        float4 gb = *(const float4*)&Ah[(size_t)sbv[r] * DD + c0];
        float4 gc = *(const float4*)&Cu[(size_t)sbm[r] * DD + c0];
        float4 o = acc[i];
        add4(o, bp); add4(o, ga); add4(o, gb); add4(o, gc);
        scale4(o, nb);
        add4(lsum, o); sqacc4(lsq, o);
        *(float4*)&e_pre[(size_t)rb * DD + c0] = o;
      }
    }
  }
  __syncthreads();
  *(float4*)&red[tr][c0] = lsum;
  __syncthreads();
  const int slot = (blockIdx.x & (NSLOT - 1)) * DD;
  if (tid < DD) {
    float s = 0.f;
#pragma unroll
    for (int t = 0; t < 16; ++t) s += red[t][tid];
    atomicAdd(&psum[slot + tid], s);
  }
  __syncthreads();
  *(float4*)&red[tr][c0] = lsq;
  __syncthreads();
  if (tid < DD) {
    float s = 0.f;
#pragma unroll
    for (int t = 0; t < 16; ++t) s += red[t][tid];
    atomicAdd(&psq[slot + tid], s);
  }
}

// ---------------- BN finalize: scale/shift (direct stats) ----------------
__global__ void bnfinal_kernel(const float* __restrict__ ssum, const float* __restrict__ ssq,
                               const float* __restrict__ gamma, const float* __restrict__ beta,
                               float invN, float* __restrict__ scale, float* __restrict__ shift) {
  int j = threadIdx.x;
  float m = ssum[j] * invN;
  float v = ssq[j] * invN - m * m;
  float sc = gamma[j] * rsqrtf(v + 1e-5f);
  scale[j] = sc;
  shift[j] = beta[j] - m * sc;
}

// ---------------- BN finalize from NSLOT slot partials ----------------
__global__ void bnfinal_slots_kernel(const float* __restrict__ psum, const float* __restrict__ psq,
                                     const float* __restrict__ gamma, const float* __restrict__ beta,
                                     float invN, float* __restrict__ scale, float* __restrict__ shift) {
  int j = threadIdx.x;
  float s = 0.f, q = 0.f;
#pragma unroll 8
  for (int t = 0; t < NSLOT; ++t) {
    s += psum[t * DD + j];
    q += psq[t * DD + j];
  }
  float m = s * invN;
  float v = q * invN - m * m;
  float sc = gamma[j] * rsqrtf(v + 1e-5f);
  scale[j] = sc;
  shift[j] = beta[j] - m * sc;
}

// ---------------- vectorized BN+ELU in place (used for u only) ----------------
__global__ void bn_elu_vec_kernel(float* __restrict__ x, long n4,
                                  const float* __restrict__ scale,
                                  const float* __restrict__ shift) {
  long stride = (long)gridDim.x * blockDim.x;
  for (long i = blockIdx.x * (long)blockDim.x + threadIdx.x; i < n4; i += stride) {
    float4 v = ((float4*)x)[i];
    int c0 = (int)((i & 15) << 2);
    float4 sc = *(const float4*)&scale[c0];
    float4 sh = *(const float4*)&shift[c0];
    v.x = elu_f(fmaf(v.x, sc.x, sh.x));
    v.y = elu_f(fmaf(v.y, sc.y, sh.y));
    v.z = elu_f(fmaf(v.z, sc.z, sh.z));
    v.w = elu_f(fmaf(v.w, sc.w, sh.w));
    ((float4*)x)[i] = v;
  }
}

// ---------------- fused pull aggregation + atom update ----------------
// ONE WAVE PER ATOM, exact grid, lane = column. Pairwise-unrolled edge loop.
// Gathers RAW e_pre, applies BN+ELU inline (fast-exp variant):
//  gate = sig(elu(e_pre*sc_e+sh_e))
//  h_pre = (Dhb[a] + sum(gate*Eh[other])/(sum(gate)+eps) + Fu[a2m]) * norm_atom
// Dhb aliases hpre (out_h): each thread reads its element then overwrites it.
__global__ __launch_bounds__(BLK) void agg_fused_kernel(
    const float* __restrict__ e_pre, const float* __restrict__ Eh,
    const float* __restrict__ Dhb, const float* __restrict__ Fu,
    const int* __restrict__ a2m, const float* __restrict__ nrm,
    const float* __restrict__ sc_e, const float* __restrict__ sh_e,
    const int* __restrict__ start, const int* __restrict__ deg,
    const int2* __restrict__ adj, int na,
    float* __restrict__ hpre,
    float* __restrict__ psum, float* __restrict__ psq) {
  const int tid = threadIdx.x;
  const int lane = tid & 63;
  const int wv = tid >> 6;
  const int wid = blockIdx.x * (BLK >> 6) + wv;
  float lsum = 0.f, lsq = 0.f;
  if (wid < na) {
    // independent row-level loads — issue ahead of the edge chain
    float dh = Dhb[(size_t)wid * DD + lane];
    float fu = Fu[(size_t)a2m[wid] * DD + lane];
    float nr = nrm[wid];
    float sce = sc_e[lane], she = sh_e[lane];
    int s = start[wid], d = deg[wid];
    float num = 0.f, den = 0.f;
    int k = 0;
    for (; k + 2 <= d; k += 2) {
      int2 e0 = adj[s + k];
      int2 e1 = adj[s + k + 1];
      float ep0 = e_pre[(size_t)e0.x * DD + lane];
      float eh0 = Eh[(size_t)e0.y * DD + lane];
      float ep1 = e_pre[(size_t)e1.x * DD + lane];
      float eh1 = Eh[(size_t)e1.y * DD + lane];
      float sg0 = sigmoid_fast(elu_fast(fmaf(ep0, sce, she)));
      float sg1 = sigmoid_fast(elu_fast(fmaf(ep1, sce, she)));
      num = fmaf(sg0, eh0, num); den += sg0;
      num = fmaf(sg1, eh1, num); den += sg1;
    }
    if (k < d) {
      int2 e0 = adj[s + k];
      float ep = e_pre[(size_t)e0.x * DD + lane];
      float eh = Eh[(size_t)e0.y * DD + lane];
      float sg = sigmoid_fast(elu_fast(fmaf(ep, sce, she)));
      num = fmaf(sg, eh, num); den += sg;
    }
    float o = (dh + num / (den + 1e-6f) + fu) * nr;
    hpre[(size_t)wid * DD + lane] = o;
    lsum = o;
    lsq = o * o;
  }
  __shared__ __align__(16) float red[BLK / 64][DD];
  red[wv][lane] = lsum;
  __syncthreads();
  if (tid < DD) {
    float s4 = red[0][tid] + red[1][tid] + red[2][tid] + red[3][tid];
    atomicAdd(&psum[(blockIdx.x & (NSLOT - 1)) * DD + tid], s4);
  }
  __syncthreads();
  red[wv][lane] = lsq;
  __syncthreads();
  if (tid < DD) {
    float s4 = red[0][tid] + red[1][tid] + red[2][tid] + red[3][tid];
    atomicAdd(&psq[(blockIdx.x & (NSLOT - 1)) * DD + tid], s4);
  }
}

// ---------------- merged mol row-sums + BN+ELU applier (4-way MLP unroll) ----------------
__global__ __launch_bounds__(BLK) void molsum2_kernel(
    float* __restrict__ rowsA, const int* __restrict__ start_ma,
    const int* __restrict__ cnta, const int* __restrict__ lista,
    const float* __restrict__ scA, const float* __restrict__ shA,
    float* __restrict__ rowsB, const int* __restrict__ start_mb,
    const int* __restrict__ cntb, const int* __restrict__ listb,
    const float* __restrict__ scB, const float* __restrict__ shB,
    int nm, float* __restrict__ msa, float* __restrict__ msb) {
  int wid = (int)((blockIdx.x * (unsigned)blockDim.x + threadIdx.x) >> 6);
  int lane = threadIdx.x & 63;
  if (wid >= 2 * nm) return;
  float* rows;
  const int* list;
  float* out;
  float sc, sh;
  int m, s, c;
  if (wid < nm) {
    m = wid; rows = rowsA; list = lista; out = msa;
    s = start_ma[m]; c = cnta[m];
    sc = scA[lane]; sh = shA[lane];
  } else {
    m = wid - nm; rows = rowsB; list = listb; out = msb;
    s = start_mb[m]; c = cntb[m];
    sc = scB[lane]; sh = shB[lane];
  }
  float acc = 0.f;
  int k = 0;
  for (; k + 4 <= c; k += 4) {
    int j0 = list[s + k], j1 = list[s + k + 1], j2 = list[s + k + 2], j3 = list[s + k + 3];
    size_t i0 = (size_t)j0 * DD + lane;
    size_t i1 = (size_t)j1 * DD + lane;
    size_t i2 = (size_t)j2 * DD + lane;
    size_t i3 = (size_t)j3 * DD + lane;
    float v0 = rows[i0];
    float v1 = rows[i1];
    float v2 = rows[i2];
    float v3 = rows[i3];
    float t0 = elu_fast(fmaf(v0, sc, sh));
    float t1 = elu_fast(fmaf(v1, sc, sh));
    float t2 = elu_fast(fmaf(v2, sc, sh));
    float t3 = elu_fast(fmaf(v3, sc, sh));
    rows[i0] = t0;
    rows[i1] = t1;
    rows[i2] = t2;
    rows[i3] = t3;
    acc += (t0 + t1) + (t2 + t3);
  }
  for (; k + 2 <= c; k += 2) {
    size_t i0 = (size_t)list[s + k] * DD + lane;
    size_t i1 = (size_t)list[s + k + 1] * DD + lane;
    float v0 = rows[i0];
    float v1 = rows[i1];
    float t0 = elu_fast(fmaf(v0, sc, sh));
    float t1 = elu_fast(fmaf(v1, sc, sh));
    rows[i0] = t0;
    rows[i1] = t1;
    acc += t0 + t1;
  }
  if (k < c) {
    size_t i0 = (size_t)list[s + k] * DD + lane;
    float t0 = elu_fast(fmaf(rows[i0], sc, sh));
    rows[i0] = t0;
    acc += t0;
  }
  out[(size_t)m * DD + lane] = acc;
}

// ---------------- global pass: u_pre = msa/cnt_a@W6 [+b6] + msb/cnt_b@W7 [+b7] + u@W8+b8 ----------------
__global__ __launch_bounds__(BLK) void global1_kernel(
    const float* __restrict__ u, int nrows,
    const float* __restrict__ W6, const float* __restrict__ W7, const float* __restrict__ W8,
    const float* __restrict__ b6, const float* __restrict__ b7, const float* __restrict__ b8,
    const float* __restrict__ msa, const float* __restrict__ msb,
    const int* __restrict__ cnta, const int* __restrict__ cntb,
    float* __restrict__ upre,
    float* __restrict__ ssum, float* __restrict__ ssq) {
  __shared__ __align__(16) float xsu[TILE][DD + 4];
  __shared__ __align__(16) float xsa[TILE][DD + 4];
  __shared__ __align__(16) float xsb[TILE][DD + 4];
  __shared__ __align__(16) float w6s[DD][DD];
  __shared__ __align__(16) float w7s[DD][DD];
  __shared__ __align__(16) float w8s[DD][DD];
  __shared__ float sfa[TILE], sfb[TILE];   // bias masks (cnt>0)
  __shared__ __align__(16) float red[16][DD];
  const int tid = threadIdx.x;
  const int base = blockIdx.x * TILE;
  int rows = nrows - base; if (rows > TILE) rows = TILE;
  for (int l = tid; l < DD * DD; l += BLK) {
    int r = l >> 6, c = l & 63;
    w6s[r][c] = W6[l];
    w7s[r][c] = W7[l];
    w8s[r][c] = W8[l];
  }
  for (int l = tid; l < TILE * DD; l += BLK) {
    int r = l >> 6, c = l & 63;
    bool v = r < rows;
    float ca = 1.f, cb = 1.f;
    if (v) {
      int ia = cnta[base + r], ib = cntb[base + r];
      ca = ia > 0 ? (float)ia : 1.f;
      cb = ib > 0 ? (float)ib : 1.f;
    }
    xsu[r][c] = v ? u[(size_t)(base + r) * DD + c] : 0.f;
    xsa[r][c] = v ? msa[(size_t)(base + r) * DD + c] / ca : 0.f;
    xsb[r][c] = v ? msb[(size_t)(base + r) * DD + c] / cb : 0.f;
  }
  if (tid < TILE) {
    bool v = tid < rows;
    sfa[tid] = (v && cnta[base + tid] > 0) ? 1.f : 0.f;
    sfb[tid] = (v && cntb[base + tid] > 0) ? 1.f : 0.f;
  }
  __syncthreads();
  const int tr = tid >> 4, tc = tid & 15, r0 = tr * 4, c0 = tc * 4;
  float4 acc[4];
#pragma unroll
  for (int i = 0; i < 4; ++i) acc[i] = make_float4(0.f, 0.f, 0.f, 0.f);
  matmul_tile(xsu, w8s, r0, c0, acc);
  matmul_tile(xsa, w6s, r0, c0, acc);
  matmul_tile(xsb, w7s, r0, c0, acc);
  float4 b6v = *(const float4*)&b6[c0];
  float4 b7v = *(const float4*)&b7[c0];
  float4 b8v = *(const float4*)&b8[c0];
  float4 lsum = make_float4(0.f, 0.f, 0.f, 0.f);
  float4 lsq  = make_float4(0.f, 0.f, 0.f, 0.f);
#pragma unroll
  for (int i = 0; i < 4; ++i) {
    int r = r0 + i;
    if (r < rows) {
      size_t rb = (size_t)(base + r) * DD + c0;
      float fa = sfa[r], fb = sfb[r];
      float4 o = acc[i];
      o.x += b8v.x + fa * b6v.x + fb * b7v.x;
      o.y += b8v.y + fa * b6v.y + fb * b7v.y;
      o.z += b8v.z + fa * b6v.z + fb * b7v.z;
      o.w += b8v.w + fa * b6v.w + fb * b7v.w;
      add4(lsum, o); sqacc4(lsq, o);
      *(float4*)&upre[rb] = o;
    }
  }
  __syncthreads();
  *(float4*)&red[tr][c0] = lsum;
  __syncthreads();
  if (tid < DD) {
    float s = 0.f;
#pragma unroll
    for (int t = 0; t < 16; ++t) s += red[t][tid];
    atomicAdd(&ssum[tid], s);
  }
  __syncthreads();
  *(float4*)&red[tr][c0] = lsq;
  __syncthreads();
  if (tid < DD) {
    float s = 0.f;
#pragma unroll
    for (int t = 0; t < 16; ++t) s += red[t][tid];
    atomicAdd(&ssq[tid], s);
  }
}

extern "C" void kernel_launch(void* const* d_in, const int* in_sizes, int n_in,
                              void* d_out, int out_size, void* d_ws, size_t ws_size,
                              hipStream_t stream) {
  const float* h         = (const float*)d_in[0];
  const float* e         = (const float*)d_in[1];
  const float* u         = (const float*)d_in[2];
  const float* norm_atom = (const float*)d_in[3];
  const float* norm_bond = (const float*)d_in[4];
  const float* Ws        = (const float*)d_in[5];
  const float* bsarr     = (const float*)d_in[6];
  const float* bn_gamma  = (const float*)d_in[7];
  const float* bn_beta   = (const float*)d_in[8];
  const int* bond_u      = (const int*)d_in[9];
  const int* bond_v      = (const int*)d_in[10];
  const int* a2m         = (const int*)d_in[11];
  const int* b2m         = (const int*)d_in[12];

  const int NA = in_sizes[0] / DD;
  const int NB = in_sizes[1] / DD;
  const int NM = in_sizes[2] / DD;

  float* out_h = (float*)d_out;
  float* out_e = out_h + (size_t)NA * DD;
  float* out_u = out_e + (size_t)NB * DD;

  // ---- workspace layout (~146 MB) ----
  float* f     = (float*)d_ws;
  float* Ah    = f;                            // NA*64
  float* Eh    = Ah + (size_t)NA * DD;         // NA*64
  float* Cu    = Eh + (size_t)NA * DD;         // NM*64
  float* Fu    = Cu + (size_t)NM * DD;         // NM*64
  float* msa   = Fu + (size_t)NM * DD;         // NM*64 (mol sum of h_new)
  float* msb   = msa + (size_t)NM * DD;        // NM*64 (mol sum of e_new)
  // Dh lives in out_h's region (dead until agg reads-then-overwrites it)
  float* Dhb   = out_h;
  // zeroed block starts here:
  float* stats = msb + (size_t)NM * DD;        // 256: sum_u, sq_u, pad
  float* sum_u = stats, *sq_u = stats + 64;
  float* psum_h = stats + 256;                 // NSLOT*64
  float* psq_h  = psum_h + NSLOT * DD;         // NSLOT*64
  float* psum_e = psq_h + NSLOT * DD;          // NSLOT*64
  float* psq_e  = psum_e + NSLOT * DD;         // NSLOT*64
  int* deg     = (int*)(psq_e + NSLOT * DD);   // NA
  int* cur     = deg + NA;                     // NA
  int* cnta_i  = cur + NA;                     // NM
  int* cntb_i  = cnta_i + NM;                  // NM
  int* cur_ma  = cntb_i + NM;                  // NM
  int* cur_mb  = cur_ma + NM;                  // NM
  int* gcounts = cur_mb + NM;                  // 4
  // zeroed block ends here.
  float* bnp   = (float*)(gcounts + 4);        // 6*64
  float* sc_e = bnp, *sh_e = bnp + 64;
  float* sc_h = bnp + 128, *sh_h = bnp + 192;
  float* sc_u = bnp + 256, *sh_u = bnp + 320;
  int* start    = (int*)(bnp + 384);           // NA
  int* start_ma = start + NA;                  // NM
  int* start_mb = start_ma + NM;               // NM
  int* lista    = start_mb + NM;               // NA
  int* listb    = lista + NA;                  // NB
  int2* adj     = (int2*)(listb + NB);         // 2*NB (8B each)

  const float* W0 = Ws + 0 * 4096; const float* b0 = bsarr + 0 * 64;
  const float* W1 = Ws + 1 * 4096; const float* b1 = bsarr + 1 * 64;
  const float* W2 = Ws + 2 * 4096; const float* b2 = bsarr + 2 * 64;
  const float* W3 = Ws + 3 * 4096; const float* b3 = bsarr + 3 * 64;
  const float* W4 = Ws + 4 * 4096; const float* b4 = bsarr + 4 * 64;
  const float* W5 = Ws + 5 * 4096; const float* b5 = bsarr + 5 * 64;
  const float* W6 = Ws + 6 * 4096; const float* b6 = bsarr + 6 * 64;
  const float* W7 = Ws + 7 * 4096; const float* b7 = bsarr + 7 * 64;
  const float* W8 = Ws + 8 * 4096; const float* b8 = bsarr + 8 * 64;

  const int tiles_a = (NA + TILE - 1) / TILE;
  const int tiles_b = (NB + TILE - 1) / TILE;
  const int tiles_m = (NM + TILE - 1) / TILE;

  // zero: stats(256) + 4 slot-partial arrays + deg + cur + mol counters + gcounts (contiguous)
  size_t zbytes = (256 + (size_t)NSLOT * DD * 4) * sizeof(float)
                + ((size_t)NA * 2 + (size_t)NM * 4 + 4) * sizeof(int);
  hipMemsetAsync(stats, 0, zbytes, stream);

  // counts + degrees
  cnt_kernel<<<(NA + NB + BLK - 1) / BLK, BLK, 0, stream>>>(a2m, NA, b2m, NB,
                                                            bond_u, bond_v,
                                                            cnta_i, cntb_i, deg);
  // CSR builds
  seg_alloc_kernel<<<(NA + BLK - 1) / BLK, BLK, 0, stream>>>(deg, NA, start, gcounts + 0);
  seg_alloc_kernel<<<(NM + BLK - 1) / BLK, BLK, 0, stream>>>(cnta_i, NM, start_ma, gcounts + 1);
  seg_alloc_kernel<<<(NM + BLK - 1) / BLK, BLK, 0, stream>>>(cntb_i, NM, start_mb, gcounts + 2);
  fill_kernel<<<(NB + BLK - 1) / BLK, BLK, 0, stream>>>(bond_u, bond_v, NB, start, cur, adj);
  fill_mol_kernel<<<(NA + NB + BLK - 1) / BLK, BLK, 0, stream>>>(a2m, NA, b2m, NB,
                                                                 start_ma, cur_ma, lista,
                                                                 start_mb, cur_mb, listb);

  // triple linear on h (3-phase LDS): Ah, Eh (ws) + Dh (out_h region) — one read of h
  lin3_kernel<<<tiles_a, BLK, 0, stream>>>(h, NA, W0, b0, Ah, W4, b4, Eh, W3, b3, Dhb);
  lin2_kernel<<<tiles_m, BLK, 0, stream>>>(u, NM, W2, b2, Cu, W5, b5, Fu);

  int nblk_b = tiles_b < 2048 ? tiles_b : 2048;
  bond1_kernel<<<nblk_b, BLK, 0, stream>>>(e, NB, tiles_b, W1, b1, Ah, Cu,
                                           bond_u, bond_v, b2m, norm_bond,
                                           out_e, psum_e, psq_e);
  bnfinal_slots_kernel<<<1, 64, 0, stream>>>(psum_e, psq_e, bn_gamma + 0, bn_beta + 0,
                                             1.f / (float)NB, sc_e, sh_e);

  // fused pull aggregation + atom update -> out_h = h_pre ; slot-partial BN stats.
  agg_fused_kernel<<<(NA + 3) / 4, BLK, 0, stream>>>(out_e, Eh, Dhb, Fu, a2m, norm_atom,
                                                     sc_e, sh_e,
                                                     start, deg, adj, NA,
                                                     out_h, psum_h, psq_h);
  bnfinal_slots_kernel<<<1, 64, 0, stream>>>(psum_h, psq_h, bn_gamma + 64, bn_beta + 64,
                                             1.f / (float)NA, sc_h, sh_h);

  // merged mol row-sums + BN+ELU applier: transforms out_h (h_pre->h_new) and
  // out_e (e_pre->e_new) in place while accumulating msa/msb. No atomics.
  molsum2_kernel<<<(2 * NM + 3) / 4, BLK, 0, stream>>>(out_h, start_ma, cnta_i, lista, sc_h, sh_h,
                                                       out_e, start_mb, cntb_i, listb, sc_e, sh_e,
                                                       NM, msa, msb);

  global1_kernel<<<tiles_m, BLK, 0, stream>>>(u, NM, W6, W7, W8, b6, b7, b8,
                                              msa, msb, cnta_i, cntb_i,
                                              out_u, sum_u, sq_u);
  bnfinal_kernel<<<1, 64, 0, stream>>>(sum_u, sq_u, bn_gamma + 128, bn_beta + 128,
                                       1.f / (float)NM, sc_u, sh_u);
  {
    long n4 = (long)NM * (DD / 4);
    int blocks = (int)((n4 + BLK - 1) / BLK); if (blocks > 2048) blocks = 2048;
    bn_elu_vec_kernel<<<blocks, BLK, 0, stream>>>(out_u, n4, sc_u, sh_u);
  }
}